// Round 7
// baseline (943.174 us; speedup 1.0000x reference)
//
#include <hip/hip_runtime.h>
#include <hip/hip_bf16.h>

// WMSA round 3: MFMA (bf16) fused kernel. Buffers confirmed f32 (WRITE_SIZE evidence).
// One block (256 thr = 4 waves) per window; wave wv owns output rows [16wv, 16wv+16).
// Pre-kernel converts weights to bf16 into d_ws.

#define CH    96
#define MMTOK 49
#define HWD   224

typedef __attribute__((ext_vector_type(8))) __bf16 bfrag;
typedef __attribute__((ext_vector_type(4))) float  f4;
#define MFMA(a,b,c) __builtin_amdgcn_mfma_f32_16x16x32_bf16(a,b,c,0,0,0)

// ws layout (bf16 element offsets)
#define WS_QW  0        // qkv_w [288][96]
#define WS_QB  27648    // qkv_b [288]
#define WS_OW  27936    // out_w [96][96]
#define WS_OB  37152    // out_b [96]
#define WS_BT  37248    // bias_table [507]
#define WS_TOT 37755

// LDS pitches (bf16 elems). Chosen so pitch-in-dwords mod 32 avoids heavy
// bank conflicts on ds_read_b128 (pitch/2 mod 32: 104->20, 216->12, 88->12).
#define PW_WIN 104
#define PW_W   104
#define PW_QK  216
#define PW_VT  88
#define PW_P   88

extern "C" __global__ void __launch_bounds__(256)
cvt_weights(const float* __restrict__ qw, const float* __restrict__ qb,
            const float* __restrict__ ow, const float* __restrict__ ob,
            const float* __restrict__ bt, __hip_bfloat16* __restrict__ ws)
{
    int i = blockIdx.x * 256 + threadIdx.x;
    if (i >= WS_TOT) return;
    float v;
    if      (i < WS_QB) v = qw[i];
    else if (i < WS_OW) v = qb[i - WS_QB];
    else if (i < WS_OB) v = ow[i - WS_OW];
    else if (i < WS_BT) v = ob[i - WS_OB];
    else                v = bt[i - WS_BT];
    ws[i] = __float2bfloat16(v);
}

extern "C" __global__ void __launch_bounds__(256)
wmsa_mfma(const float* __restrict__ x,
          const __hip_bfloat16* __restrict__ ws,
          float* __restrict__ out)
{
    __shared__ __align__(16) __hip_bfloat16 s_win[64 * PW_WIN];  // window in, later 'stack'
    __shared__ __align__(16) __hip_bfloat16 s_w  [96 * PW_W];    // weight chunk; P overlays
    __shared__ __align__(16) __hip_bfloat16 s_qk [64 * PW_QK];   // [t][h*64 + (K?32:0) + d]
    __shared__ __align__(16) __hip_bfloat16 s_vT [96 * PW_VT];   // [(h*32+d)][t]
    __shared__ float s_bias[507];

    const int tid  = threadIdx.x;
    // XCD-bijective swizzle: gridDim.x % 8 == 0 (16384)
    const int cpx  = gridDim.x >> 3;
    const int wid  = (blockIdx.x & 7) * cpx + (blockIdx.x >> 3);
    const int b    = wid >> 10;
    const int w    = wid & 1023;
    const int h0   = (w >> 5) * 7;
    const int w0   = (w & 31) * 7;
    const int lane = tid & 63;
    const int wv   = tid >> 6;
    const int lr   = lane & 15;
    const int lg   = lane >> 4;
    const int trow = wv * 16 + lg * 4;   // C-tile row base for this lane

    const __hip_bfloat16* QW = ws + WS_QW;
    const __hip_bfloat16* QB = ws + WS_QB;
    const __hip_bfloat16* OW = ws + WS_OW;
    const __hip_bfloat16* OB = ws + WS_OB;
    const __hip_bfloat16* BT = ws + WS_BT;

    // ---- stage bias table (f32 in LDS) ----
    for (int i = tid; i < 507; i += 256) s_bias[i] = __bfloat162float(BT[i]);

    // ---- load window -> s_win bf16, rows 49..63 zeroed ----
    for (int idx = tid; idx < 64 * CH; idx += 256) {
        int t = idx & 63, c = idx >> 6;
        float v = 0.f;
        if (t < MMTOK) {
            int i = t / 7, j = t - i * 7;
            v = x[((b * CH + c) * HWD + h0 + i) * HWD + w0 + j];
        }
        s_win[t * PW_WIN + c] = __float2bfloat16(v);
    }
    __syncthreads();

    // A-fragments for QKV GEMM (rows wv*16+lr, K=96 = 3 kblocks)
    bfrag aq[3];
    #pragma unroll
    for (int k = 0; k < 3; ++k)
        aq[k] = *(const bfrag*)&s_win[(wv * 16 + lr) * PW_WIN + k * 32 + lg * 8];

    // ==== QKV GEMM, 3 chunks of 96 output cols (chunk ob == head ob) ====
    for (int ob = 0; ob < 3; ++ob) {
        if (ob) __syncthreads();                 // prev chunk GEMM done before restage
        for (int idx = tid; idx < 96 * 12; idx += 256) {
            int r = idx / 12, c8 = (idx - r * 12) * 8;
            *(uint4*)&s_w[r * PW_W + c8] = *(const uint4*)&QW[(ob * 96 + r) * 96 + c8];
        }
        __syncthreads();

        f4 acc[6];
        #pragma unroll
        for (int n = 0; n < 6; ++n) {
            float bb = __bfloat162float(QB[ob * 96 + n * 16 + lr]);
            acc[n] = f4{bb, bb, bb, bb};
        }
        #pragma unroll
        for (int k = 0; k < 3; ++k)
            #pragma unroll
            for (int n = 0; n < 6; ++n) {
                bfrag bf = *(const bfrag*)&s_w[(n * 16 + lr) * PW_W + k * 32 + lg * 8];
                acc[n] = MFMA(aq[k], bf, acc[n]);
            }

        // C-store: n=0,1 -> Q ; n=2,3 -> K ; n=4,5 -> V(transposed)
        #pragma unroll
        for (int n = 0; n < 6; ++n) {
            int part = n >> 1;
            int d = ((n & 1) << 4) + lr;
            #pragma unroll
            for (int r = 0; r < 4; ++r) {
                __hip_bfloat16 hv = __float2bfloat16(acc[n][r]);
                int t = trow + r;
                if (part < 2) s_qk[t * PW_QK + ob * 64 + part * 32 + d] = hv;
                else          s_vT[(ob * 32 + d) * PW_VT + t] = hv;
            }
        }
    }
    __syncthreads();

    // ==== attention ====
    __hip_bfloat16* s_P = s_w;                  // overlay: [64][PW_P]
    const float inv_scale = 0.0180421959f;      // sqrt(3)/96

    int a1[4];
    #pragma unroll
    for (int r = 0; r < 4; ++r) {
        int p = trow + r, i1 = p / 7, j1 = p - 7 * i1;
        a1[r] = (i1 * 13 + j1) * 3;
    }
    int a2[4]; bool qok[4];
    #pragma unroll
    for (int n = 0; n < 4; ++n) {
        int q = n * 16 + lr, i2 = q / 7, j2 = q - 7 * i2;
        a2[n] = (i2 * 13 + j2) * 3;
        qok[n] = (q < MMTOK);
    }

    for (int h = 0; h < 3; ++h) {
        // QK^T: scores strip [16 p][64 q] in registers
        bfrag qa = *(const bfrag*)&s_qk[(wv * 16 + lr) * PW_QK + h * 64 + lg * 8];
        f4 sc[4];
        #pragma unroll
        for (int n = 0; n < 4; ++n) {
            bfrag kb = *(const bfrag*)&s_qk[(n * 16 + lr) * PW_QK + h * 64 + 32 + lg * 8];
            f4 z = f4{0.f, 0.f, 0.f, 0.f};
            sc[n] = MFMA(qa, kb, z);
        }

        // scale + bias, row-max / exp / row-sum via 16-lane shuffle reduce
        float vals[4][4], mr[4], sum[4];
        #pragma unroll
        for (int r = 0; r < 4; ++r) mr[r] = -1e30f;
        #pragma unroll
        for (int n = 0; n < 4; ++n)
            #pragma unroll
            for (int r = 0; r < 4; ++r) {
                int bidx = a1[r] - a2[n] + 252 + h;
                bidx = bidx < 0 ? 0 : (bidx > 506 ? 506 : bidx);
                float s = qok[n] ? sc[n][r] * inv_scale + s_bias[bidx] : -1e30f;
                vals[n][r] = s;
                mr[r] = fmaxf(mr[r], s);
            }
        #pragma unroll
        for (int m = 1; m <= 8; m <<= 1)
            #pragma unroll
            for (int r = 0; r < 4; ++r) mr[r] = fmaxf(mr[r], __shfl_xor(mr[r], m));
        #pragma unroll
        for (int r = 0; r < 4; ++r) sum[r] = 0.f;
        #pragma unroll
        for (int n = 0; n < 4; ++n)
            #pragma unroll
            for (int r = 0; r < 4; ++r) {
                float e = qok[n] ? __expf(vals[n][r] - mr[r]) : 0.f;
                vals[n][r] = e;
                sum[r] += e;
            }
        #pragma unroll
        for (int m = 1; m <= 8; m <<= 1)
            #pragma unroll
            for (int r = 0; r < 4; ++r) sum[r] += __shfl_xor(sum[r], m);
        float inv[4];
        #pragma unroll
        for (int r = 0; r < 4; ++r) inv[r] = 1.0f / sum[r];

        // write normalized P (bf16), zeros for q>=49 keep PV K-padding clean
        #pragma unroll
        for (int n = 0; n < 4; ++n)
            #pragma unroll
            for (int r = 0; r < 4; ++r)
                s_P[(trow + r) * PW_P + n * 16 + lr] = __float2bfloat16(vals[n][r] * inv[r]);
        __syncthreads();   // safety: guarantee P visible before frag reads

        // PV: O strip [16 p][32 d] = P[16][64] x V[64][32]
        bfrag pa[2];
        #pragma unroll
        for (int kb2 = 0; kb2 < 2; ++kb2)
            pa[kb2] = *(const bfrag*)&s_P[(wv * 16 + lr) * PW_P + kb2 * 32 + lg * 8];
        #pragma unroll
        for (int n = 0; n < 2; ++n) {
            f4 oc = f4{0.f, 0.f, 0.f, 0.f};
            #pragma unroll
            for (int kb2 = 0; kb2 < 2; ++kb2) {
                bfrag vb = *(const bfrag*)&s_vT[(h * 32 + n * 16 + lr) * PW_VT + kb2 * 32 + lg * 8];
                oc = MFMA(pa[kb2], vb, oc);
            }
            #pragma unroll
            for (int r = 0; r < 4; ++r)
                s_win[(trow + r) * PW_WIN + h * 32 + n * 16 + lr] = __float2bfloat16(oc[r]);
        }
        __syncthreads();   // P reused next head
    }

    // ==== output projection ====
    for (int idx = tid; idx < 96 * 12; idx += 256) {
        int r = idx / 12, c8 = (idx - r * 12) * 8;
        *(uint4*)&s_w[r * PW_W + c8] = *(const uint4*)&OW[r * 96 + c8];
    }
    __syncthreads();

    bfrag sa[3];
    #pragma unroll
    for (int k = 0; k < 3; ++k)
        sa[k] = *(const bfrag*)&s_win[(wv * 16 + lr) * PW_WIN + k * 32 + lg * 8];
    f4 yac[6];
    #pragma unroll
    for (int n = 0; n < 6; ++n) {
        float bb = __bfloat162float(OB[n * 16 + lr]);
        yac[n] = f4{bb, bb, bb, bb};
    }
    #pragma unroll
    for (int k = 0; k < 3; ++k)
        #pragma unroll
        for (int n = 0; n < 6; ++n) {
            bfrag wb = *(const bfrag*)&s_w[(n * 16 + lr) * PW_W + k * 32 + lg * 8];
            yac[n] = MFMA(sa[k], wb, yac[n]);
        }

    // store: flat = w*49 + t ; out[b][o][flat/224][flat%224]
    #pragma unroll
    for (int n = 0; n < 6; ++n) {
        int o = n * 16 + lr;
        #pragma unroll
        for (int r = 0; r < 4; ++r) {
            int t = trow + r;
            if (t < MMTOK) {
                int flat = w * MMTOK + t;
                int ho = flat / HWD, wo = flat - ho * HWD;
                out[((b * CH + o) * HWD + ho) * HWD + wo] = yac[n][r];
            }
        }
    }
}

extern "C" void kernel_launch(void* const* d_in, const int* in_sizes, int n_in,
                              void* d_out, int out_size, void* d_ws, size_t ws_size,
                              hipStream_t stream) {
    const float* x  = (const float*)d_in[0];
    const float* qw = (const float*)d_in[1];
    const float* qb = (const float*)d_in[2];
    const float* bt = (const float*)d_in[3];
    const float* ow = (const float*)d_in[4];
    const float* ob = (const float*)d_in[5];
    float* out      = (float*)d_out;
    __hip_bfloat16* ws = (__hip_bfloat16*)d_ws;

    cvt_weights<<<(WS_TOT + 255) / 256, 256, 0, stream>>>(qw, qb, ow, ob, bt, ws);

    int B = in_sizes[0] / (CH * HWD * HWD);      // 16
    int nblocks = B * 1024;                      // one block per window (16384, %8==0)
    wmsa_mfma<<<nblocks, 256, 0, stream>>>(x, ws, out);
}

// Round 8
// 749.683 us; speedup vs baseline: 1.2581x; 1.2581x over previous
//
#include <hip/hip_runtime.h>
#include <hip/hip_bf16.h>

// WMSA round 4: latency-oriented restructure.
//  - per-head pipeline (QKV chunk ob == head ob -> attention ob immediately)
//  - no LDS weight staging: B-frags are 16B global loads from L2-resident bf16 ws
//  - LDS 38.4 KB -> 4 blocks/CU (16 waves/CU), 10 barriers/block
// One block (256 thr = 4 waves) per window; wave wv owns rows [16wv,16wv+16).

#define CH    96
#define MMTOK 49
#define HWD   224

typedef __attribute__((ext_vector_type(8))) __bf16 bfrag;
typedef __attribute__((ext_vector_type(4))) float  f4;
#define MFMA(a,b,c) __builtin_amdgcn_mfma_f32_16x16x32_bf16(a,b,c,0,0,0)

// ws layout (bf16 element offsets): qkv_w [288][96], out_w [96][96]
#define WS_OW  27648
#define WS_TOT 36864

// LDS pitches (bf16 elems); pitch/2 mod 32: 104->20, 72->4 (2-way max on b128 reads)
#define PW_WIN 104
#define PW_QK  72
#define PW_VT  72
#define PW_P   72

extern "C" __global__ void __launch_bounds__(256)
cvt_weights(const float* __restrict__ qw, const float* __restrict__ ow,
            __hip_bfloat16* __restrict__ ws)
{
    int i = blockIdx.x * 256 + threadIdx.x;
    if (i >= WS_TOT) return;
    ws[i] = __float2bfloat16(i < WS_OW ? qw[i] : ow[i - WS_OW]);
}

extern "C" __global__ void __launch_bounds__(256, 4)
wmsa_mfma(const float* __restrict__ x,
          const __hip_bfloat16* __restrict__ ws,
          const float* __restrict__ qkvb,   // f32 [288]
          const float* __restrict__ bt,     // f32 [507]
          const float* __restrict__ outb,   // f32 [96]
          float* __restrict__ out)
{
    __shared__ __align__(16) __hip_bfloat16 s_win[64 * PW_WIN]; // input A, later O (stack)
    __shared__ __align__(16) __hip_bfloat16 s_qk [64 * PW_QK];  // [t][ d(Q):0..31 | d(K):32..63 ]
    __shared__ __align__(16) __hip_bfloat16 s_vT [32 * PW_VT];  // [d][t], one head
    __shared__ __align__(16) __hip_bfloat16 s_P  [64 * PW_P];   // normalized P, one head
    __shared__ float s_bias[507];

    const int tid  = threadIdx.x;
    // XCD-bijective swizzle (gridDim.x = 16384, %8==0)
    const int cpx  = gridDim.x >> 3;
    const int wid  = (blockIdx.x & 7) * cpx + (blockIdx.x >> 3);
    const int b    = wid >> 10;
    const int w    = wid & 1023;
    const int h0   = (w >> 5) * 7;
    const int w0   = (w & 31) * 7;
    const int lane = tid & 63;
    const int wv   = tid >> 6;
    const int lr   = lane & 15;
    const int lg   = lane >> 4;
    const int trow = wv * 16 + lg * 4;     // C-tile row base

    const __hip_bfloat16* QW = ws;
    const __hip_bfloat16* OW = ws + WS_OW;

    // ---- stage bias table (f32) ----
    for (int i = tid; i < 507; i += 256) s_bias[i] = bt[i];

    // ---- load window -> s_win bf16, rows 49..63 zeroed ----
    for (int idx = tid; idx < 64 * CH; idx += 256) {
        int t = idx & 63, c = idx >> 6;
        float v = 0.f;
        if (t < MMTOK) {
            int i = t / 7, j = t - i * 7;
            v = x[((b * CH + c) * HWD + h0 + i) * HWD + w0 + j];
        }
        s_win[t * PW_WIN + c] = __float2bfloat16(v);
    }
    __syncthreads();                                   // [1]

    // A-fragments (rows wv*16+lr, K=96 = 3 kblocks); s_win input data dead after this
    bfrag aq[3];
    #pragma unroll
    for (int k = 0; k < 3; ++k)
        aq[k] = *(const bfrag*)&s_win[(wv * 16 + lr) * PW_WIN + k * 32 + lg * 8];

    // bias-gather index precompute
    int a1[4];
    #pragma unroll
    for (int r = 0; r < 4; ++r) {
        int p = trow + r, i1 = p / 7, j1 = p - 7 * i1;
        a1[r] = (i1 * 13 + j1) * 3;
    }
    int a2[4]; bool qok[4];
    #pragma unroll
    for (int n = 0; n < 4; ++n) {
        int q = n * 16 + lr, i2 = q / 7, j2 = q - 7 * i2;
        a2[n] = (i2 * 13 + j2) * 3;
        qok[n] = (q < MMTOK);
    }

    const float inv_scale = 0.0180421959f;             // sqrt(3)/96

    // ==== per-head: QKV chunk GEMM -> attention -> O strip ====
    for (int ob = 0; ob < 3; ++ob) {
        // --- GEMM chunk ob: C[64 rows][96 cols], B-frags straight from global (L2) ---
        f4 acc[6];
        #pragma unroll
        for (int n = 0; n < 6; ++n) {
            float bb = qkvb[ob * 96 + n * 16 + lr];
            acc[n] = f4{bb, bb, bb, bb};
        }
        #pragma unroll
        for (int k = 0; k < 3; ++k)
            #pragma unroll
            for (int n = 0; n < 6; ++n) {
                bfrag bf = *(const bfrag*)&QW[(ob * 96 + n * 16 + lr) * 96 + k * 32 + lg * 8];
                acc[n] = MFMA(aq[k], bf, acc[n]);
            }

        __syncthreads();   // [A] prev head's s_qk/s_vT/s_P reads complete

        // C-store: n=0,1 -> Q ; n=2,3 -> K ; n=4,5 -> V^T
        #pragma unroll
        for (int n = 0; n < 6; ++n) {
            int part = n >> 1;
            int d = ((n & 1) << 4) + lr;
            #pragma unroll
            for (int r = 0; r < 4; ++r) {
                __hip_bfloat16 hv = __float2bfloat16(acc[n][r]);
                int t = trow + r;
                if (part < 2) s_qk[t * PW_QK + part * 32 + d] = hv;
                else          s_vT[d * PW_VT + t] = hv;
            }
        }
        __syncthreads();   // [B] Q,K,V visible

        // --- QK^T: score strip [16 p][64 q] in registers ---
        bfrag qa = *(const bfrag*)&s_qk[(wv * 16 + lr) * PW_QK + lg * 8];
        f4 sc[4];
        #pragma unroll
        for (int n = 0; n < 4; ++n) {
            bfrag kb = *(const bfrag*)&s_qk[(n * 16 + lr) * PW_QK + 32 + lg * 8];
            f4 z = f4{0.f, 0.f, 0.f, 0.f};
            sc[n] = MFMA(qa, kb, z);
        }

        // --- softmax (row reduce across 16 lanes) ---
        float vals[4][4], mr[4], sum[4];
        #pragma unroll
        for (int r = 0; r < 4; ++r) mr[r] = -1e30f;
        #pragma unroll
        for (int n = 0; n < 4; ++n)
            #pragma unroll
            for (int r = 0; r < 4; ++r) {
                int bidx = a1[r] - a2[n] + 252 + ob;
                bidx = bidx < 0 ? 0 : (bidx > 506 ? 506 : bidx);
                float s = qok[n] ? sc[n][r] * inv_scale + s_bias[bidx] : -1e30f;
                vals[n][r] = s;
                mr[r] = fmaxf(mr[r], s);
            }
        #pragma unroll
        for (int m = 1; m <= 8; m <<= 1)
            #pragma unroll
            for (int r = 0; r < 4; ++r) mr[r] = fmaxf(mr[r], __shfl_xor(mr[r], m));
        #pragma unroll
        for (int r = 0; r < 4; ++r) sum[r] = 0.f;
        #pragma unroll
        for (int n = 0; n < 4; ++n)
            #pragma unroll
            for (int r = 0; r < 4; ++r) {
                float e = qok[n] ? __expf(vals[n][r] - mr[r]) : 0.f;
                vals[n][r] = e;
                sum[r] += e;
            }
        #pragma unroll
        for (int m = 1; m <= 8; m <<= 1)
            #pragma unroll
            for (int r = 0; r < 4; ++r) sum[r] += __shfl_xor(sum[r], m);
        float inv[4];
        #pragma unroll
        for (int r = 0; r < 4; ++r) inv[r] = 1.0f / sum[r];

        // normalized P -> LDS (zeros at q>=49 keep PV K-padding clean)
        #pragma unroll
        for (int n = 0; n < 4; ++n)
            #pragma unroll
            for (int r = 0; r < 4; ++r)
                s_P[(trow + r) * PW_P + n * 16 + lr] = __float2bfloat16(vals[n][r] * inv[r]);
        __syncthreads();   // [C] P visible

        // --- PV: O strip [16 p][32 d]; store into s_win cols [ob*32, ob*32+32) ---
        bfrag pa[2];
        #pragma unroll
        for (int kb2 = 0; kb2 < 2; ++kb2)
            pa[kb2] = *(const bfrag*)&s_P[(wv * 16 + lr) * PW_P + kb2 * 32 + lg * 8];
        #pragma unroll
        for (int n = 0; n < 2; ++n) {
            f4 oc = f4{0.f, 0.f, 0.f, 0.f};
            #pragma unroll
            for (int kb2 = 0; kb2 < 2; ++kb2) {
                bfrag vb = *(const bfrag*)&s_vT[(n * 16 + lr) * PW_VT + kb2 * 32 + lg * 8];
                oc = MFMA(pa[kb2], vb, oc);
            }
            #pragma unroll
            for (int r = 0; r < 4; ++r)
                s_win[(trow + r) * PW_WIN + ob * 32 + n * 16 + lr] = __float2bfloat16(oc[r]);
        }
        // no barrier: next iteration's [A] guards reuse; out-proj reads are wave-local
    }

    // ==== output projection (A = own strip of s_win, B from global L2) ====
    bfrag sa[3];
    #pragma unroll
    for (int k = 0; k < 3; ++k)
        sa[k] = *(const bfrag*)&s_win[(wv * 16 + lr) * PW_WIN + k * 32 + lg * 8];
    f4 yac[6];
    #pragma unroll
    for (int n = 0; n < 6; ++n) {
        float bb = outb[n * 16 + lr];
        yac[n] = f4{bb, bb, bb, bb};
    }
    #pragma unroll
    for (int k = 0; k < 3; ++k)
        #pragma unroll
        for (int n = 0; n < 6; ++n) {
            bfrag wb = *(const bfrag*)&OW[(n * 16 + lr) * 96 + k * 32 + lg * 8];
            yac[n] = MFMA(sa[k], wb, yac[n]);
        }

    // store: flat = w*49 + t ; out[b][o][flat/224][flat%224]
    #pragma unroll
    for (int n = 0; n < 6; ++n) {
        int o = n * 16 + lr;
        #pragma unroll
        for (int r = 0; r < 4; ++r) {
            int t = trow + r;
            if (t < MMTOK) {
                int flat = w * MMTOK + t;
                int ho = flat / HWD, wo = flat - ho * HWD;
                out[((b * CH + o) * HWD + ho) * HWD + wo] = yac[n][r];
            }
        }
    }
}

extern "C" void kernel_launch(void* const* d_in, const int* in_sizes, int n_in,
                              void* d_out, int out_size, void* d_ws, size_t ws_size,
                              hipStream_t stream) {
    const float* x  = (const float*)d_in[0];
    const float* qw = (const float*)d_in[1];
    const float* qb = (const float*)d_in[2];
    const float* bt = (const float*)d_in[3];
    const float* ow = (const float*)d_in[4];
    const float* ob = (const float*)d_in[5];
    float* out      = (float*)d_out;
    __hip_bfloat16* ws = (__hip_bfloat16*)d_ws;

    cvt_weights<<<(WS_TOT + 255) / 256, 256, 0, stream>>>(qw, ow, ws);

    int B = in_sizes[0] / (CH * HWD * HWD);      // 16
    int nblocks = B * 1024;                      // one block per window (16384, %8==0)
    wmsa_mfma<<<nblocks, 256, 0, stream>>>(x, ws, qb, bt, ob, out);
}

// Round 9
// 575.397 us; speedup vs baseline: 1.6392x; 1.3029x over previous
//
#include <hip/hip_runtime.h>
#include <hip/hip_bf16.h>

// WMSA round 5: break per-iteration load->use serialization.
//  - window load register-staged: 24 global loads issued batched, one drain
//  - GEMM B-fragments register double-buffered (batched L2 loads, MFMA bursts)
//  - s_setprio around MFMA bursts (4 independent blocks/CU -> role diversity)
// One block (256 thr = 4 waves) per window; wave wv owns rows [16wv,16wv+16).

#define CH    96
#define MMTOK 49
#define HWD   224
#define PLANE (HWD * HWD)

typedef __attribute__((ext_vector_type(8))) __bf16 bfrag;
typedef __attribute__((ext_vector_type(4))) float  f4;
#define MFMA(a,b,c) __builtin_amdgcn_mfma_f32_16x16x32_bf16(a,b,c,0,0,0)

// ws layout (bf16 element offsets): qkv_w [288][96], out_w [96][96]
#define WS_OW  27648
#define WS_TOT 36864

// LDS pitches (bf16 elems)
#define PW_WIN 104
#define PW_QK  72
#define PW_VT  72
#define PW_P   72

extern "C" __global__ void __launch_bounds__(256)
cvt_weights(const float* __restrict__ qw, const float* __restrict__ ow,
            __hip_bfloat16* __restrict__ ws)
{
    int i = blockIdx.x * 256 + threadIdx.x;
    if (i >= WS_TOT) return;
    ws[i] = __float2bfloat16(i < WS_OW ? qw[i] : ow[i - WS_OW]);
}

extern "C" __global__ void __launch_bounds__(256, 4)
wmsa_mfma(const float* __restrict__ x,
          const __hip_bfloat16* __restrict__ ws,
          const float* __restrict__ qkvb,   // f32 [288]
          const float* __restrict__ bt,     // f32 [507]
          const float* __restrict__ outb,   // f32 [96]
          float* __restrict__ out)
{
    __shared__ __align__(16) __hip_bfloat16 s_win[64 * PW_WIN]; // input A, later O (stack)
    __shared__ __align__(16) __hip_bfloat16 s_qk [64 * PW_QK];  // [t][ d(Q):0..31 | d(K):32..63 ]
    __shared__ __align__(16) __hip_bfloat16 s_vT [32 * PW_VT];  // [d][t], one head
    __shared__ __align__(16) __hip_bfloat16 s_P  [64 * PW_P];   // normalized P, one head
    __shared__ float s_bias[507];

    const int tid  = threadIdx.x;
    // XCD-bijective swizzle (gridDim.x = 16384, %8==0)
    const int cpx  = gridDim.x >> 3;
    const int wid  = (blockIdx.x & 7) * cpx + (blockIdx.x >> 3);
    const int b    = wid >> 10;
    const int w    = wid & 1023;
    const int h0   = (w >> 5) * 7;
    const int w0   = (w & 31) * 7;
    const int lane = tid & 63;
    const int wv   = tid >> 6;
    const int lr   = lane & 15;
    const int lg   = lane >> 4;
    const int trow = wv * 16 + lg * 4;     // C-tile row base

    const __hip_bfloat16* QW = ws;
    const __hip_bfloat16* OW = ws + WS_OW;

    // ---- stage bias table (f32) ----
    for (int i = tid; i < 507; i += 256) s_bias[i] = bt[i];

    // ---- window load: t = lane (fixed), c = wv + 4k. Batch all 24 loads. ----
    {
        const int t  = lane;
        const int tt = (t < MMTOK) ? t : 0;           // clamped for safe address
        const int ti = tt / 7, tj = tt - ti * 7;
        const float* xp = x + ((size_t)(b * CH + wv) * PLANE)
                            + (size_t)(h0 + ti) * HWD + (w0 + tj);
        float rx[24];
        #pragma unroll
        for (int k = 0; k < 24; ++k)
            rx[k] = xp[(size_t)k * 4 * PLANE];        // c = wv + 4k
        const float zmask = (t < MMTOK) ? 1.f : 0.f;
        #pragma unroll
        for (int k = 0; k < 24; ++k)
            s_win[t * PW_WIN + wv + 4 * k] = __float2bfloat16(rx[k] * zmask);
    }
    __syncthreads();                                   // [1]

    // A-fragments (rows wv*16+lr, K=96 = 3 kblocks)
    bfrag aq[3];
    #pragma unroll
    for (int k = 0; k < 3; ++k)
        aq[k] = *(const bfrag*)&s_win[(wv * 16 + lr) * PW_WIN + k * 32 + lg * 8];

    // bias-gather index precompute
    int a1[4];
    #pragma unroll
    for (int r = 0; r < 4; ++r) {
        int p = trow + r, i1 = p / 7, j1 = p - 7 * i1;
        a1[r] = (i1 * 13 + j1) * 3;
    }
    int a2[4]; bool qok[4];
    #pragma unroll
    for (int n = 0; n < 4; ++n) {
        int q = n * 16 + lr, i2 = q / 7, j2 = q - 7 * i2;
        a2[n] = (i2 * 13 + j2) * 3;
        qok[n] = (q < MMTOK);
    }

    const float inv_scale = 0.0180421959f;             // sqrt(3)/96

    // ==== per-head: QKV chunk GEMM -> attention -> O strip ====
    for (int ob = 0; ob < 3; ++ob) {
        // --- GEMM chunk ob, register-double-buffered B-frags from L2 ---
        const __hip_bfloat16* QWrow = QW + (ob * 96 + lr) * 96 + lg * 8;
        f4 acc[6];
        #pragma unroll
        for (int n = 0; n < 6; ++n) {
            float bb = qkvb[ob * 96 + n * 16 + lr];
            acc[n] = f4{bb, bb, bb, bb};
        }
        bfrag b0[6], b1[6];
        #pragma unroll
        for (int n = 0; n < 6; ++n) b0[n] = *(const bfrag*)&QWrow[n * 16 * 96 + 0 * 32];
        #pragma unroll
        for (int n = 0; n < 6; ++n) b1[n] = *(const bfrag*)&QWrow[n * 16 * 96 + 1 * 32];
        __builtin_amdgcn_s_setprio(1);
        #pragma unroll
        for (int n = 0; n < 6; ++n) acc[n] = MFMA(aq[0], b0[n], acc[n]);
        __builtin_amdgcn_s_setprio(0);
        #pragma unroll
        for (int n = 0; n < 6; ++n) b0[n] = *(const bfrag*)&QWrow[n * 16 * 96 + 2 * 32];
        __builtin_amdgcn_s_setprio(1);
        #pragma unroll
        for (int n = 0; n < 6; ++n) acc[n] = MFMA(aq[1], b1[n], acc[n]);
        #pragma unroll
        for (int n = 0; n < 6; ++n) acc[n] = MFMA(aq[2], b0[n], acc[n]);
        __builtin_amdgcn_s_setprio(0);

        __syncthreads();   // [A] prev head's s_qk/s_vT/s_P reads complete

        // C-store: n=0,1 -> Q ; n=2,3 -> K ; n=4,5 -> V^T
        #pragma unroll
        for (int n = 0; n < 6; ++n) {
            int part = n >> 1;
            int d = ((n & 1) << 4) + lr;
            #pragma unroll
            for (int r = 0; r < 4; ++r) {
                __hip_bfloat16 hv = __float2bfloat16(acc[n][r]);
                int t = trow + r;
                if (part < 2) s_qk[t * PW_QK + part * 32 + d] = hv;
                else          s_vT[d * PW_VT + t] = hv;
            }
        }
        __syncthreads();   // [B] Q,K,V visible

        // --- QK^T: score strip [16 p][64 q] in registers ---
        bfrag qa = *(const bfrag*)&s_qk[(wv * 16 + lr) * PW_QK + lg * 8];
        f4 sc[4];
        __builtin_amdgcn_s_setprio(1);
        #pragma unroll
        for (int n = 0; n < 4; ++n) {
            bfrag kb = *(const bfrag*)&s_qk[(n * 16 + lr) * PW_QK + 32 + lg * 8];
            f4 z = f4{0.f, 0.f, 0.f, 0.f};
            sc[n] = MFMA(qa, kb, z);
        }
        __builtin_amdgcn_s_setprio(0);

        // --- softmax (row reduce across 16 lanes) ---
        float vals[4][4], mr[4], sum[4];
        #pragma unroll
        for (int r = 0; r < 4; ++r) mr[r] = -1e30f;
        #pragma unroll
        for (int n = 0; n < 4; ++n)
            #pragma unroll
            for (int r = 0; r < 4; ++r) {
                int bidx = a1[r] - a2[n] + 252 + ob;
                bidx = bidx < 0 ? 0 : (bidx > 506 ? 506 : bidx);
                float s = qok[n] ? sc[n][r] * inv_scale + s_bias[bidx] : -1e30f;
                vals[n][r] = s;
                mr[r] = fmaxf(mr[r], s);
            }
        #pragma unroll
        for (int m = 1; m <= 8; m <<= 1)
            #pragma unroll
            for (int r = 0; r < 4; ++r) mr[r] = fmaxf(mr[r], __shfl_xor(mr[r], m));
        #pragma unroll
        for (int r = 0; r < 4; ++r) sum[r] = 0.f;
        #pragma unroll
        for (int n = 0; n < 4; ++n)
            #pragma unroll
            for (int r = 0; r < 4; ++r) {
                float e = qok[n] ? __expf(vals[n][r] - mr[r]) : 0.f;
                vals[n][r] = e;
                sum[r] += e;
            }
        #pragma unroll
        for (int m = 1; m <= 8; m <<= 1)
            #pragma unroll
            for (int r = 0; r < 4; ++r) sum[r] += __shfl_xor(sum[r], m);
        float inv[4];
        #pragma unroll
        for (int r = 0; r < 4; ++r) inv[r] = 1.0f / sum[r];

        // normalized P -> LDS (zeros at q>=49 keep PV K-padding clean)
        #pragma unroll
        for (int n = 0; n < 4; ++n)
            #pragma unroll
            for (int r = 0; r < 4; ++r)
                s_P[(trow + r) * PW_P + n * 16 + lr] = __float2bfloat16(vals[n][r] * inv[r]);
        __syncthreads();   // [C] P visible

        // --- PV: O strip [16 p][32 d]; store into s_win cols [ob*32, ob*32+32) ---
        bfrag pa[2];
        #pragma unroll
        for (int kb2 = 0; kb2 < 2; ++kb2)
            pa[kb2] = *(const bfrag*)&s_P[(wv * 16 + lr) * PW_P + kb2 * 32 + lg * 8];
        __builtin_amdgcn_s_setprio(1);
        #pragma unroll
        for (int n = 0; n < 2; ++n) {
            f4 oc = f4{0.f, 0.f, 0.f, 0.f};
            #pragma unroll
            for (int kb2 = 0; kb2 < 2; ++kb2) {
                bfrag vb = *(const bfrag*)&s_vT[(n * 16 + lr) * PW_VT + kb2 * 32 + lg * 8];
                oc = MFMA(pa[kb2], vb, oc);
            }
            #pragma unroll
            for (int r = 0; r < 4; ++r)
                s_win[(trow + r) * PW_WIN + ob * 32 + n * 16 + lr] = __float2bfloat16(oc[r]);
        }
        __builtin_amdgcn_s_setprio(0);
        // no barrier: next iteration's [A] guards reuse; out-proj reads are wave-local
    }

    // ==== output projection (A = own strip of s_win, B from global L2) ====
    bfrag sa[3];
    #pragma unroll
    for (int k = 0; k < 3; ++k)
        sa[k] = *(const bfrag*)&s_win[(wv * 16 + lr) * PW_WIN + k * 32 + lg * 8];
    f4 yac[6];
    #pragma unroll
    for (int n = 0; n < 6; ++n) {
        float bb = outb[n * 16 + lr];
        yac[n] = f4{bb, bb, bb, bb};
    }
    {
        const __hip_bfloat16* OWrow = OW + lr * 96 + lg * 8;
        bfrag c0[6], c1[6];
        #pragma unroll
        for (int n = 0; n < 6; ++n) c0[n] = *(const bfrag*)&OWrow[n * 16 * 96 + 0 * 32];
        #pragma unroll
        for (int n = 0; n < 6; ++n) c1[n] = *(const bfrag*)&OWrow[n * 16 * 96 + 1 * 32];
        __builtin_amdgcn_s_setprio(1);
        #pragma unroll
        for (int n = 0; n < 6; ++n) yac[n] = MFMA(sa[0], c0[n], yac[n]);
        __builtin_amdgcn_s_setprio(0);
        #pragma unroll
        for (int n = 0; n < 6; ++n) c0[n] = *(const bfrag*)&OWrow[n * 16 * 96 + 2 * 32];
        __builtin_amdgcn_s_setprio(1);
        #pragma unroll
        for (int n = 0; n < 6; ++n) yac[n] = MFMA(sa[1], c1[n], yac[n]);
        #pragma unroll
        for (int n = 0; n < 6; ++n) yac[n] = MFMA(sa[2], c0[n], yac[n]);
        __builtin_amdgcn_s_setprio(0);
    }

    // store: flat = w*49 + t ; out[b][o][flat/224][flat%224]
    #pragma unroll
    for (int r = 0; r < 4; ++r) {
        int t = trow + r;
        if (t < MMTOK) {
            int flat = w * MMTOK + t;
            int ho = flat / HWD, wo = flat - ho * HWD;
            float* op = out + (size_t)(b * CH + lr) * PLANE + (size_t)ho * HWD + wo;
            #pragma unroll
            for (int n = 0; n < 6; ++n)
                op[(size_t)n * 16 * PLANE] = yac[n][r];
        }
    }
}

extern "C" void kernel_launch(void* const* d_in, const int* in_sizes, int n_in,
                              void* d_out, int out_size, void* d_ws, size_t ws_size,
                              hipStream_t stream) {
    const float* x  = (const float*)d_in[0];
    const float* qw = (const float*)d_in[1];
    const float* qb = (const float*)d_in[2];
    const float* bt = (const float*)d_in[3];
    const float* ow = (const float*)d_in[4];
    const float* ob = (const float*)d_in[5];
    float* out      = (float*)d_out;
    __hip_bfloat16* ws = (__hip_bfloat16*)d_ws;

    cvt_weights<<<(WS_TOT + 255) / 256, 256, 0, stream>>>(qw, ow, ws);

    int B = in_sizes[0] / (CH * HWD * HWD);      // 16
    int nblocks = B * 1024;                      // one block per window (16384, %8==0)
    wmsa_mfma<<<nblocks, 256, 0, stream>>>(x, ws, qb, bt, ob, out);
}